// Round 1
// 113.179 us; speedup vs baseline: 1.0490x; 1.0490x over previous
//
#include <hip/hip_runtime.h>
#include <stdint.h>
#include <math.h>

#define BSZ 4096
#define DIM 768
#define TEMP 0.07f

typedef short short8 __attribute__((ext_vector_type(8)));
typedef float f32x4 __attribute__((ext_vector_type(4)));

// ---------- helpers ----------

__device__ __forceinline__ uint16_t f2bf(float f) {
  uint32_t u = __float_as_uint(f);
  uint32_t r = (u + 0x7FFFu + ((u >> 16) & 1u)) >> 16;  // RNE
  return (uint16_t)r;
}

__device__ __forceinline__ void gll16(const void* g, void* l) {
  __builtin_amdgcn_global_load_lds(
      (__attribute__((address_space(1))) void*)(uintptr_t)g,
      (__attribute__((address_space(3))) void*)l,
      16, 0, 0);
}

// sorted-desc top-5 insert
__device__ __forceinline__ void ins5(float v, float& a, float& b, float& c,
                                     float& d, float& e) {
  if (v > e) {
    e = v;
    if (e > d) { float t = d; d = e; e = t;
      if (d > c) { t = c; c = d; d = t;
        if (c > b) { t = b; b = c; c = t;
          if (b > a) { t = a; a = b; b = t; } } } }
  }
}

// ---------- K1: normalize + cast to bf16 ----------
__global__ __launch_bounds__(256) void k_norm(const float* __restrict__ text,
                                              const float* __restrict__ table,
                                              uint16_t* __restrict__ tn,
                                              uint16_t* __restrict__ zn) {
  int row = blockIdx.x & (BSZ - 1);
  bool isTable = blockIdx.x >= BSZ;
  const float* src = (isTable ? table : text) + (size_t)row * DIM;
  uint16_t* dst = (isTable ? zn : tn) + (size_t)row * DIM;
  int tid = threadIdx.x;

  float x0 = src[tid];
  float x1 = src[tid + 256];
  float x2 = src[tid + 512];
  float ss = x0 * x0 + x1 * x1 + x2 * x2;
  #pragma unroll
  for (int off = 32; off >= 1; off >>= 1) ss += __shfl_xor(ss, off);
  __shared__ float wss[4];
  if ((tid & 63) == 0) wss[tid >> 6] = ss;
  __syncthreads();
  float inv = rsqrtf(wss[0] + wss[1] + wss[2] + wss[3]);
  dst[tid]       = f2bf(x0 * inv);
  dst[tid + 256] = f2bf(x1 * inv);
  dst[tid + 512] = f2bf(x2 * inv);
}

// ---------- K2: sim = Zn @ Tn^T  (256x256 tile, BK=64, counted-vmcnt pipeline)
// 512 threads = 8 waves (2M x 4N), wave tile 128x64.
// LDS (dynamic 128 KiB): buf0 A @0, B @32768; buf1 A @65536, B @98304.
// Layout per operand per K-tile: [kc 0..7][row 0..255][8 bf16] (16B chunks).
// Staging: wave w owns kc=w; 4 rowgroups x 64 rows per operand, 8 gll16/thread/tile.
//
// Schedule (T3/T4-lite): split compute by m-half so tile t+2's stage starts
// mid-compute of tile t, into the regions of buf[t&1] already fully consumed:
//   phase A: m0-3 (reads A rg0,rg2 + all B; B fragments held in regs)
//   bar; issue t+2: A rg0,rg2 + B rg0-3 (6 loads)
//   phase B: m4-7 (reads only A rg1,rg3 - disjoint from in-flight writes)
//   bar; issue t+2: A rg1,rg3 (2 loads)
//   vmcnt(8): retire tile t+1's 8 loads (issued a full tile ago); keep t+2's 8 in flight
//   bar
// Invariant at each iter start: 8 loads outstanding (= next tile's).
__global__ __launch_bounds__(512, 2) void k_gemm(const uint16_t* __restrict__ Zb,
                                                 const uint16_t* __restrict__ Tb,
                                                 float* __restrict__ sim) {
  extern __shared__ __attribute__((aligned(16))) char lds[];

  int tid = threadIdx.x;
  int wave = tid >> 6, lane = tid & 63;
  int wm = wave >> 2, wn = wave & 3;
  int brow = (blockIdx.x >> 4) << 8;
  int bcol = (blockIdx.x & 15) << 8;

  f32x4 acc[8][4] = {};

  const uint16_t* gA = Zb + (size_t)brow * DIM + wave * 8;
  const uint16_t* gB = Tb + (size_t)bcol * DIM + wave * 8;
  char* ldsA = lds + (wave << 12);  // this wave's kc slab

  int kqg = lane >> 4;                          // 0..3
  int rbyte = ((wm << 7) + (lane & 15)) << 4;   // A row base byte within kc-slab
  int cbyte = ((wn << 6) + (lane & 15)) << 4;   // B row base byte

  auto SA = [&](int t2, int bb, int rg) {
    gll16(gA + (size_t)t2 * 64 + (size_t)(rg * 64 + lane) * DIM,
          ldsA + bb + rg * 1024);
  };
  auto SB = [&](int t2, int bb, int rg) {
    gll16(gB + (size_t)t2 * 64 + (size_t)(rg * 64 + lane) * DIM,
          ldsA + bb + 32768 + rg * 1024);
  };

  auto LOADB = [&](int bb, short8 (&bf)[2][4]) {
    #pragma unroll
    for (int ks = 0; ks < 2; ++ks) {
      const char* Bb = lds + bb + (((ks << 2) + kqg) << 12) + 32768;
      #pragma unroll
      for (int n = 0; n < 4; ++n)
        bf[ks][n] = *(const short8*)(Bb + cbyte + (n << 8));
    }
  };
  auto PHASE = [&](int bb, int mlo, short8 (&bf)[2][4]) {
    __builtin_amdgcn_s_setprio(1);
    #pragma unroll
    for (int ks = 0; ks < 2; ++ks) {
      const char* Ab = lds + bb + (((ks << 2) + kqg) << 12);
      #pragma unroll
      for (int m = 0; m < 4; ++m) {
        short8 af = *(const short8*)(Ab + rbyte + ((mlo + m) << 8));
        #pragma unroll
        for (int n = 0; n < 4; ++n)
          acc[mlo + m][n] = __builtin_amdgcn_mfma_f32_16x16x32_bf16(
              af, bf[ks][n], acc[mlo + m][n], 0, 0, 0);
      }
    }
    __builtin_amdgcn_s_setprio(0);
  };

  // ---- prologue: stage tiles 0 and 1 (16 loads); land tile 0, keep 1 in flight
  #pragma unroll
  for (int rg = 0; rg < 4; ++rg) { SA(0, 0, rg); SB(0, 0, rg); }
  #pragma unroll
  for (int rg = 0; rg < 4; ++rg) { SA(1, 65536, rg); SB(1, 65536, rg); }
  asm volatile("s_waitcnt vmcnt(8)" ::: "memory");
  __builtin_amdgcn_s_barrier();

  // ---- main loop: tiles 0..9, staging tiles 2..11
  #pragma unroll 2
  for (int t = 0; t < 10; ++t) {
    int bb = (t & 1) << 16;
    short8 bf[2][4];
    LOADB(bb, bf);
    PHASE(bb, 0, bf);
    __builtin_amdgcn_s_barrier();
    // regions A rg0,rg2 and all of B (in regs) of buf bb are now dead: stage t+2
    SA(t + 2, bb, 0); SA(t + 2, bb, 2);
    SB(t + 2, bb, 0); SB(t + 2, bb, 1); SB(t + 2, bb, 2); SB(t + 2, bb, 3);
    PHASE(bb, 4, bf);
    __builtin_amdgcn_s_barrier();
    SA(t + 2, bb, 1); SA(t + 2, bb, 3);
    asm volatile("s_waitcnt vmcnt(8)" ::: "memory");  // retire tile t+1's loads only
    __builtin_amdgcn_s_barrier();
  }

  // ---- epilogue tiles: 10 (buf0), 11 (buf1) — no further staging
  {
    short8 bf[2][4];
    LOADB(0, bf);
    PHASE(0, 0, bf);
    PHASE(0, 4, bf);
  }
  asm volatile("s_waitcnt vmcnt(0)" ::: "memory");
  __builtin_amdgcn_s_barrier();
  {
    short8 bf[2][4];
    LOADB(65536, bf);
    PHASE(65536, 0, bf);
    PHASE(65536, 4, bf);
  }

  // epilogue: C/D layout col=lane&15, row=(lane>>4)*4+reg
  int crow0 = brow + (wm << 7) + ((lane >> 4) << 2);
  int ccol0 = bcol + (wn << 6) + (lane & 15);
  #pragma unroll
  for (int m = 0; m < 8; ++m)
    #pragma unroll
    for (int n = 0; n < 4; ++n)
      #pragma unroll
      for (int r = 0; r < 4; ++r)
        sim[(size_t)(crow0 + m * 16 + r) * BSZ + (ccol0 + n * 16)] = acc[m][n][r];
}

// ---------- K3: fused tile pass — row & col partial top-5 ----------
__global__ __launch_bounds__(256) void k_tile(const float* __restrict__ sim,
                                              float* __restrict__ rp,
                                              float* __restrict__ cp) {
  __shared__ float lds[128 * 64];      // [row][col^(row&63)]
  __shared__ float sc[64 * 4 * 5];
  int tid = threadIdx.x;
  int tr = blockIdx.x >> 5, tc = blockIdx.x & 31;
  int row0 = tr << 7, col0 = tc << 7;

  int q = tid >> 6;
  int c = tid & 63;
  int rrow = tid & 127;
  int hh = tid >> 7;

  float r0 = -1e30f, r1 = -1e30f, r2 = -1e30f, r3 = -1e30f, r4 = -1e30f;

  #pragma unroll
  for (int h = 0; h < 2; ++h) {
    int gcol = col0 + h * 64 + c;
    float c0 = -1e30f, c1 = -1e30f, c2 = -1e30f, c3 = -1e30f, c4 = -1e30f;
    #pragma unroll 8
    for (int r = 0; r < 32; ++r) {
      int row = q * 32 + r;
      int grow = row0 + row;
      float v = sim[(size_t)grow * BSZ + gcol];
      float vm = (grow == gcol) ? -1e30f : v;
      lds[row * 64 + (c ^ (row & 63))] = vm;
      ins5(vm, c0, c1, c2, c3, c4);
    }
    {
      float* s = sc + (c * 4 + q) * 5;
      s[0] = c0; s[1] = c1; s[2] = c2; s[3] = c3; s[4] = c4;
    }
    __syncthreads();

    #pragma unroll 8
    for (int cc = 0; cc < 32; ++cc) {
      int ccol = hh * 32 + cc;
      float v = lds[rrow * 64 + (ccol ^ (rrow & 63))];
      ins5(v, r0, r1, r2, r3, r4);
    }
    if (tid < 64) {
      float m0 = -1e30f, m1 = -1e30f, m2 = -1e30f, m3 = -1e30f, m4 = -1e30f;
      #pragma unroll
      for (int qq = 0; qq < 4; ++qq) {
        const float* s = sc + (tid * 4 + qq) * 5;
        ins5(s[0], m0, m1, m2, m3, m4);
        ins5(s[1], m0, m1, m2, m3, m4);
        ins5(s[2], m0, m1, m2, m3, m4);
        ins5(s[3], m0, m1, m2, m3, m4);
        ins5(s[4], m0, m1, m2, m3, m4);
      }
      float* p = cp + ((size_t)(col0 + h * 64 + tid) * 32 + tr) * 5;
      p[0] = m0; p[1] = m1; p[2] = m2; p[3] = m3; p[4] = m4;
    }
    __syncthreads();
  }

  if (hh == 1) {
    float* s = sc + rrow * 5;
    s[0] = r0; s[1] = r1; s[2] = r2; s[3] = r3; s[4] = r4;
  }
  __syncthreads();
  if (hh == 0) {
    const float* s = sc + rrow * 5;
    ins5(s[0], r0, r1, r2, r3, r4);
    ins5(s[1], r0, r1, r2, r3, r4);
    ins5(s[2], r0, r1, r2, r3, r4);
    ins5(s[3], r0, r1, r2, r3, r4);
    ins5(s[4], r0, r1, r2, r3, r4);
    float* p = rp + ((size_t)(row0 + rrow) * 32 + tc) * 5;
    p[0] = r0; p[1] = r1; p[2] = r2; p[3] = r3; p[4] = r4;
  }
}

// ---------- K4: merge partials (wave per line) + loss ----------
__global__ __launch_bounds__(256) void k_merge(const float* __restrict__ sim,
                                               const float* __restrict__ rp,
                                               const float* __restrict__ cp,
                                               float* __restrict__ lossbuf) {
  int wave = threadIdx.x >> 6, lane = threadIdx.x & 63;
  int wid = blockIdx.x * 4 + wave;
  bool isCol = wid >= BSZ;
  int line = isCol ? wid - BSZ : wid;
  const float* src = (isCol ? cp : rp) + (size_t)line * 160;

  float t0 = -1e30f, t1 = -1e30f, t2 = -1e30f, t3 = -1e30f, t4 = -1e30f;
  ins5(src[lane], t0, t1, t2, t3, t4);
  ins5(src[lane + 64], t0, t1, t2, t3, t4);
  if (lane < 32) ins5(src[lane + 128], t0, t1, t2, t3, t4);

  float top[5];
  #pragma unroll
  for (int e = 0; e < 5; e++) {
    float m = t0;
    #pragma unroll
    for (int off = 32; off >= 1; off >>= 1) m = fmaxf(m, __shfl_xor(m, off));
    unsigned long long msk = __ballot(t0 == m);
    int owner = __ffsll(msk) - 1;
    if (lane == owner) { t0 = t1; t1 = t2; t2 = t3; t3 = t4; t4 = -1e30f; }
    top[e] = m;
  }

  if (lane == 0) {
    float pos = sim[(size_t)line * BSZ + line] / TEMP;
    float l0 = top[0] / TEMP, l1 = top[1] / TEMP, l2 = top[2] / TEMP,
          l3 = top[3] / TEMP, l4 = top[4] / TEMP;
    float mx = fmaxf(pos, fmaxf(fmaxf(l0, l1), fmaxf(fmaxf(l2, l3), l4)));
    float s = expf(pos - mx) + expf(l0 - mx) + expf(l1 - mx) +
              expf(l2 - mx) + expf(l3 - mx) + expf(l4 - mx);
    lossbuf[wid] = mx + logf(s) - pos;
  }
}

// ---------- K5: final reduction ----------
__global__ __launch_bounds__(256) void k_reduce(const float* __restrict__ losses,
                                                float* __restrict__ out) {
  int tid = threadIdx.x;
  float s = 0.f;
  for (int i = tid; i < 2 * BSZ; i += 256) s += losses[i];
  #pragma unroll
  for (int off = 32; off >= 1; off >>= 1) s += __shfl_xor(s, off);
  __shared__ float wss[4];
  if ((tid & 63) == 0) wss[tid >> 6] = s;
  __syncthreads();
  if (tid == 0) out[0] = (wss[0] + wss[1] + wss[2] + wss[3]) / (2.0f * BSZ);
}

// ---------- launcher ----------
extern "C" void kernel_launch(void* const* d_in, const int* in_sizes, int n_in,
                              void* d_out, int out_size, void* d_ws, size_t ws_size,
                              hipStream_t stream) {
  const float* text = (const float*)d_in[0];
  const float* table = (const float*)d_in[1];
  float* out = (float*)d_out;
  float* sim = out + 1;  // d_out = [loss, sim(4096x4096)]

  uint16_t* Zb = (uint16_t*)d_ws;
  uint16_t* Tb = Zb + (size_t)BSZ * DIM;
  float* lossbuf = (float*)(Tb + (size_t)BSZ * DIM);  // 2*BSZ floats

  // rp/cp alias the Zb/Tb region (dead after k_gemm; stream-ordered).
  float* rp = (float*)d_ws;                  // [4096][32][5]
  float* cp = rp + (size_t)BSZ * 32 * 5;     // [4096][32][5]

  k_norm<<<2 * BSZ, 256, 0, stream>>>(text, table, Tb, Zb);
  k_gemm<<<(BSZ / 256) * (BSZ / 256), 512, 131072, stream>>>(Zb, Tb, sim);
  k_tile<<<32 * 32, 256, 0, stream>>>(sim, rp, cp);
  k_merge<<<2 * BSZ / 4, 256, 0, stream>>>(sim, rp, cp, lossbuf);
  k_reduce<<<1, 256, 0, stream>>>(lossbuf, out);
}